// Round 1
// baseline (871.372 us; speedup 1.0000x reference)
//
#include <hip/hip_runtime.h>

// HierarchicalRouter: 32768 tokens x D=2048 fp32.
// Outputs (concatenated in d_out): final_weights [32768,2], dispatch_mask [32768,64], router_loss [1].
// Memory-bound: must stream x (256 MB). Weights (20x2048 fp32 = 160 KB) staged in LDS
// in 40 KB D-chunks, amortized over 16 tokens/block to keep L2 weight traffic ~330 MB.

#define NTOK    32768
#define DIM     2048
#define NG      16      // router groups (rows of Wg)
#define GS      4       // experts per group (rows of We)
#define NE      64      // total experts
#define NR      20      // NG + GS stacked weight rows
#define DC      512     // D-chunk staged in LDS (20*512*4 = 40 KB)
#define NCHUNK  (DIM / DC)
#define TPB     256
#define TPW     4       // tokens per wave
#define TPBK    16      // tokens per block (4 waves * 4)
#define NSHADOW 32      // shadow copies of expert_load to spread atomic contention

__global__ __launch_bounds__(TPB, 3) void router_main(
    const float* __restrict__ x,
    const float* __restrict__ Wg,
    const float* __restrict__ We,
    float* __restrict__ fw_out,
    float* __restrict__ dm_out,
    float* __restrict__ ws)
{
    __shared__ float wlds[NR * DC];   // 40 KB weight chunk
    __shared__ float lds_load[NE];    // per-block expert load
    __shared__ float lds_z;           // per-block z-loss partial

    const int tid  = threadIdx.x;
    const int lane = tid & 63;
    const int wave = tid >> 6;
    const long t_base = (long)blockIdx.x * TPBK + wave * TPW;

    if (tid < NE) lds_load[tid] = 0.0f;
    if (tid == 0) lds_z = 0.0f;

    float acc[TPW][NR];
    #pragma unroll
    for (int t = 0; t < TPW; ++t)
        #pragma unroll
        for (int r = 0; r < NR; ++r) acc[t][r] = 0.0f;

    for (int c = 0; c < NCHUNK; ++c) {
        __syncthreads();  // protect previous chunk's LDS reads (and lds_load init)
        // ---- stage 20x512 weight chunk into LDS (coalesced float4) ----
        #pragma unroll
        for (int k = 0; k < (NR * DC) / (TPB * 4); ++k) {  // 10 iters
            int f   = (k * TPB + tid) * 4;   // flat float index into 20x512 chunk
            int r   = f >> 9;                // /512
            int col = f & (DC - 1);
            const float* src = (r < NG) ? (Wg + (size_t)r * DIM)
                                        : (We + (size_t)(r - NG) * DIM);
            float4 v = *(const float4*)(src + c * DC + col);
            *(float4*)(&wlds[r * DC + col]) = v;
        }
        __syncthreads();

        // ---- accumulate: wave covers d = [c*512, c*512+512), lane gets l*4 and l*4+256 ----
        float4 xa[TPW], xb[TPW];
        #pragma unroll
        for (int t = 0; t < TPW; ++t) {
            const float4* xp = (const float4*)(x + (size_t)(t_base + t) * DIM + c * DC);
            xa[t] = xp[lane];        // 64 lanes x 16B = 1 KB contiguous
            xb[t] = xp[lane + 64];
        }
        #pragma unroll
        for (int r = 0; r < NR; ++r) {
            float4 wa = *(const float4*)(&wlds[r * DC + lane * 4]);
            float4 wb = *(const float4*)(&wlds[r * DC + 256 + lane * 4]);
            #pragma unroll
            for (int t = 0; t < TPW; ++t) {
                acc[t][r] += xa[t].x * wa.x + xa[t].y * wa.y
                           + xa[t].z * wa.z + xa[t].w * wa.w
                           + xb[t].x * wb.x + xb[t].y * wb.y
                           + xb[t].z * wb.z + xb[t].w * wb.w;
            }
        }
    }

    // ---- full-wave butterfly reduce: all lanes converge to identical sums ----
    #pragma unroll
    for (int t = 0; t < TPW; ++t)
        #pragma unroll
        for (int r = 0; r < NR; ++r) {
            float v = acc[t][r];
            #pragma unroll
            for (int s = 32; s > 0; s >>= 1) v += __shfl_xor(v, s, 64);
            acc[t][r] = v;
        }

    // ---- epilogue: every lane computes all 4 tokens (redundant, cheap), then selects ----
    float fw0a[TPW], fw1a[TPW], zca[TPW];
    int   e0a[TPW], e1a[TPW];
    #pragma unroll
    for (int t = 0; t < TPW; ++t) {
        // group softmax + top-1 (compare on exp values; strict > = first-index-wins, matches np)
        float m16 = acc[t][0];
        #pragma unroll
        for (int r = 1; r < NG; ++r) m16 = fmaxf(m16, acc[t][r]);
        float den = 0.0f, bm = -1.0f; int gi = 0;
        #pragma unroll
        for (int r = 0; r < NG; ++r) {
            float e = expf(acc[t][r] - m16);
            den += e;
            if (e > bm) { bm = e; gi = r; }
        }
        float gw = bm / den;   // chosen_group_w (max softmax prob)

        // local softmax (4) + top-2
        float m4 = fmaxf(fmaxf(acc[t][NG + 0], acc[t][NG + 1]),
                         fmaxf(acc[t][NG + 2], acc[t][NG + 3]));
        float pr[GS]; float s4 = 0.0f;
        #pragma unroll
        for (int r = 0; r < GS; ++r) { pr[r] = expf(acc[t][NG + r] - m4); s4 += pr[r]; }
        float inv4 = 1.0f / s4;
        #pragma unroll
        for (int r = 0; r < GS; ++r) pr[r] *= inv4;

        int i0 = 0; float v0 = pr[0];
        #pragma unroll
        for (int r = 1; r < GS; ++r) if (pr[r] > v0) { v0 = pr[r]; i0 = r; }
        int i1 = -1; float v1 = -1.0f;
        #pragma unroll
        for (int r = 0; r < GS; ++r) if (r != i0 && pr[r] > v1) { v1 = pr[r]; i1 = r; }

        float nrm = v0 + v1 + 1e-7f;
        float w0 = v0 / nrm, w1 = v1 / nrm;
        fw0a[t] = gw * w0;
        fw1a[t] = gw * w1;
        e0a[t]  = (gi << 2) + i0;
        e1a[t]  = (gi << 2) + i1;

        float sg = 0.0f;
        #pragma unroll
        for (int r = 0; r < NG; ++r) sg += acc[t][r] * acc[t][r];
        float sl = 0.0f;
        #pragma unroll
        for (int r = 0; r < GS; ++r) sl += acc[t][NG + r] * acc[t][NG + r];
        zca[t] = sg * (1.0f / 16.0f) + sl * 0.25f;   // per-token z contribution
    }

    // select this lane's token (t = lane>>4) via cndmask chains (no dynamic reg indexing)
    const int myt = lane >> 4;
    float sf0 = fw0a[0], sf1 = fw1a[0], sz = zca[0];
    int   se0 = e0a[0],  se1 = e1a[0];
    #pragma unroll
    for (int q = 1; q < TPW; ++q) {
        if (myt == q) { sf0 = fw0a[q]; sf1 = fw1a[q]; sz = zca[q]; se0 = e0a[q]; se1 = e1a[q]; }
    }
    const long tok = t_base + myt;

    // dispatch mask: 16 lanes per token, each lane writes one float4 (4 expert cols) — 1 KB/wave coalesced
    {
        int col4 = (lane & 15) * 4;
        float4 v;
        v.x = (col4 + 0 == se0) ? sf0 : (col4 + 0 == se1) ? sf1 : 0.0f;
        v.y = (col4 + 1 == se0) ? sf0 : (col4 + 1 == se1) ? sf1 : 0.0f;
        v.z = (col4 + 2 == se0) ? sf0 : (col4 + 2 == se1) ? sf1 : 0.0f;
        v.w = (col4 + 3 == se0) ? sf0 : (col4 + 3 == se1) ? sf1 : 0.0f;
        *(float4*)(dm_out + (size_t)tok * NE + col4) = v;
    }

    int sub = lane & 15;
    if (sub == 0) {
        fw_out[tok * 2 + 0] = sf0;
        atomicAdd(&lds_load[se0], sf0);
    } else if (sub == 1) {
        fw_out[tok * 2 + 1] = sf1;
        atomicAdd(&lds_load[se1], sf1);
    } else if (sub == 2) {
        atomicAdd(&lds_z, sz);
    }

    __syncthreads();
    if (tid < NE) atomicAdd(&ws[(blockIdx.x & (NSHADOW - 1)) * NE + tid], lds_load[tid]);
    if (tid == 0) atomicAdd(&ws[NSHADOW * NE], lds_z);
}

__global__ void router_finalize(const float* __restrict__ ws, float* __restrict__ out_loss)
{
    int e = threadIdx.x;  // 64 threads = 1 wave
    float load = 0.0f;
    #pragma unroll
    for (int s = 0; s < NSHADOW; ++s) load += ws[s * NE + e];
    float tot = load;
    #pragma unroll
    for (int s = 32; s > 0; s >>= 1) tot += __shfl_xor(tot, s, 64);
    float target = tot * (1.0f / NE);
    float dev = load - target;
    float sq = dev * dev;
    #pragma unroll
    for (int s = 32; s > 0; s >>= 1) sq += __shfl_xor(sq, s, 64);
    if (e == 0) {
        float lb = sq * (1.0f / NE);
        float z  = ws[NSHADOW * NE] * (1.0f / NTOK);
        out_loss[0] = 0.001f * (lb + z);
    }
}

extern "C" void kernel_launch(void* const* d_in, const int* in_sizes, int n_in,
                              void* d_out, int out_size, void* d_ws, size_t ws_size,
                              hipStream_t stream)
{
    const float* x  = (const float*)d_in[0];
    const float* Wg = (const float*)d_in[1];
    const float* We = (const float*)d_in[2];
    float* out = (float*)d_out;
    float* fw  = out;                                   // [32768, 2]
    float* dm  = out + (size_t)NTOK * 2;                // [32768, 64]
    float* ls  = out + (size_t)NTOK * 2 + (size_t)NTOK * NE;  // [1]
    float* ws  = (float*)d_ws;

    hipMemsetAsync(ws, 0, (NSHADOW * NE + 1) * sizeof(float), stream);
    router_main<<<NTOK / TPBK, TPB, 0, stream>>>(x, Wg, We, fw, dm, ws);
    router_finalize<<<1, 64, 0, stream>>>(ws, ls);
}

// Round 2
// 408.744 us; speedup vs baseline: 2.1318x; 2.1318x over previous
//
#include <hip/hip_runtime.h>

// HierarchicalRouter: 32768 tokens x D=2048 fp32.
// Outputs (concat in d_out): final_weights [32768,2], dispatch_mask [32768,64], router_loss [1].
// Memory-bound: stream x (256 MB) once. Round-1 lesson: register spill (acc[4][20]+epilogue
// arrays) generated 1.9 GB of scratch traffic. This version keeps peak live regs ~110:
//  - DC=256 (one float4 of x per token per chunk; no xb[])
//  - epilogue per-token sequential, scalar-only (post-butterfly sums are lane-uniform)
//  - __launch_bounds__(256,2) so the allocator has a 256-VGPR budget and never spills.

#define NTOK    32768
#define DIM     2048
#define NG      16      // router groups (rows of Wg)
#define GS      4       // experts per group (rows of We)
#define NE      64      // total experts
#define NR      20      // NG + GS stacked weight rows
#define DC      256     // D-chunk staged in LDS (20*256*4 = 20 KB)
#define NCHUNK  (DIM / DC)
#define TPB     256
#define TPW     4       // tokens per wave
#define TPBK    16      // tokens per block (4 waves * 4)
#define NSHADOW 32      // shadow copies of expert_load to spread atomic contention

__global__ __launch_bounds__(TPB, 2) void router_main(
    const float* __restrict__ x,
    const float* __restrict__ Wg,
    const float* __restrict__ We,
    float* __restrict__ fw_out,
    float* __restrict__ dm_out,
    float* __restrict__ ws)
{
    __shared__ float wlds[NR * DC];   // 20 KB weight chunk
    __shared__ float lds_load[NE];    // per-block expert load
    __shared__ float lds_z;           // per-block z-loss partial

    const int tid  = threadIdx.x;
    const int lane = tid & 63;
    const int wave = tid >> 6;
    const long t_base = (long)blockIdx.x * TPBK + wave * TPW;

    if (tid < NE) lds_load[tid] = 0.0f;
    if (tid == 0) lds_z = 0.0f;

    float acc[TPW][NR];
    #pragma unroll
    for (int t = 0; t < TPW; ++t)
        #pragma unroll
        for (int r = 0; r < NR; ++r) acc[t][r] = 0.0f;

    for (int c = 0; c < NCHUNK; ++c) {
        __syncthreads();  // protect previous chunk's LDS reads (and lds_load init)
        // ---- stage 20x256 weight chunk into LDS (coalesced float4), 5 iters ----
        #pragma unroll
        for (int k = 0; k < (NR * DC) / (TPB * 4); ++k) {
            int f   = (k * TPB + tid) * 4;   // flat float index into 20x256 chunk
            int r   = f >> 8;                // /256
            int col = f & (DC - 1);
            const float* src = (r < NG) ? (Wg + (size_t)r * DIM)
                                        : (We + (size_t)(r - NG) * DIM);
            *(float4*)(&wlds[r * DC + col]) = *(const float4*)(src + c * DC + col);
        }
        __syncthreads();

        // ---- accumulate: wave covers d = [c*256, c*256+256), lane holds float4 at lane*4 ----
        float4 xa[TPW];
        #pragma unroll
        for (int t = 0; t < TPW; ++t) {
            const float4* xp = (const float4*)(x + (size_t)(t_base + t) * DIM + c * DC);
            xa[t] = xp[lane];        // 64 lanes x 16B = 1 KB contiguous
        }
        #pragma unroll
        for (int r = 0; r < NR; ++r) {
            float4 w = *(const float4*)(&wlds[r * DC + lane * 4]);
            #pragma unroll
            for (int t = 0; t < TPW; ++t) {
                acc[t][r] += xa[t].x * w.x + xa[t].y * w.y
                           + xa[t].z * w.z + xa[t].w * w.w;
            }
        }
    }

    // ---- full-wave butterfly reduce: all lanes converge to identical sums ----
    #pragma unroll
    for (int t = 0; t < TPW; ++t)
        #pragma unroll
        for (int r = 0; r < NR; ++r) {
            float v = acc[t][r];
            #pragma unroll
            for (int s = 32; s > 0; s >>= 1) v += __shfl_xor(v, s, 64);
            acc[t][r] = v;
        }

    // ---- epilogue: tokens sequentially; scalar-only state (lane-uniform values) ----
    #pragma unroll
    for (int t = 0; t < TPW; ++t) {
        // group softmax + top-1 (strict > = first-index-wins, matches np)
        float m16 = acc[t][0];
        #pragma unroll
        for (int r = 1; r < NG; ++r) m16 = fmaxf(m16, acc[t][r]);
        float den = 0.0f, bm = -1.0f; int gi = 0;
        #pragma unroll
        for (int r = 0; r < NG; ++r) {
            float e = expf(acc[t][r] - m16);
            den += e;
            if (e > bm) { bm = e; gi = r; }
        }
        float gw = bm / den;   // chosen_group_w (max softmax prob)

        // local softmax (4) + top-2
        float m4 = fmaxf(fmaxf(acc[t][NG + 0], acc[t][NG + 1]),
                         fmaxf(acc[t][NG + 2], acc[t][NG + 3]));
        float pr[GS]; float s4 = 0.0f;
        #pragma unroll
        for (int r = 0; r < GS; ++r) { pr[r] = expf(acc[t][NG + r] - m4); s4 += pr[r]; }
        float inv4 = 1.0f / s4;
        #pragma unroll
        for (int r = 0; r < GS; ++r) pr[r] *= inv4;

        int i0 = 0; float v0 = pr[0];
        #pragma unroll
        for (int r = 1; r < GS; ++r) if (pr[r] > v0) { v0 = pr[r]; i0 = r; }
        int i1 = -1; float v1 = -1.0f;
        #pragma unroll
        for (int r = 0; r < GS; ++r) if (r != i0 && pr[r] > v1) { v1 = pr[r]; i1 = r; }

        float nrm = v0 + v1 + 1e-7f;
        float sf0 = gw * (v0 / nrm);
        float sf1 = gw * (v1 / nrm);
        int   se0 = (gi << 2) + i0;
        int   se1 = (gi << 2) + i1;

        float sg = 0.0f;
        #pragma unroll
        for (int r = 0; r < NG; ++r) sg += acc[t][r] * acc[t][r];
        float sl = 0.0f;
        #pragma unroll
        for (int r = 0; r < GS; ++r) sl += acc[t][NG + r] * acc[t][NG + r];
        float sz = sg * (1.0f / 16.0f) + sl * 0.25f;   // per-token z contribution

        const long tok = t_base + t;
        if (lane < 16) {
            int col4 = lane * 4;
            float4 v;
            v.x = (col4 + 0 == se0) ? sf0 : (col4 + 0 == se1) ? sf1 : 0.0f;
            v.y = (col4 + 1 == se0) ? sf0 : (col4 + 1 == se1) ? sf1 : 0.0f;
            v.z = (col4 + 2 == se0) ? sf0 : (col4 + 2 == se1) ? sf1 : 0.0f;
            v.w = (col4 + 3 == se0) ? sf0 : (col4 + 3 == se1) ? sf1 : 0.0f;
            *(float4*)(dm_out + (size_t)tok * NE + col4) = v;  // 16 lanes x 16B = 256B row
        } else if (lane == 16) {
            *(float2*)(fw_out + tok * 2) = make_float2(sf0, sf1);
        } else if (lane == 17) {
            atomicAdd(&lds_load[se0], sf0);
        } else if (lane == 18) {
            atomicAdd(&lds_load[se1], sf1);
        } else if (lane == 19) {
            atomicAdd(&lds_z, sz);
        }
    }

    __syncthreads();
    if (tid < NE) atomicAdd(&ws[(blockIdx.x & (NSHADOW - 1)) * NE + tid], lds_load[tid]);
    if (tid == 0) atomicAdd(&ws[NSHADOW * NE], lds_z);
}

__global__ void router_finalize(const float* __restrict__ ws, float* __restrict__ out_loss)
{
    int e = threadIdx.x;  // 64 threads = 1 wave
    float load = 0.0f;
    #pragma unroll
    for (int s = 0; s < NSHADOW; ++s) load += ws[s * NE + e];
    float tot = load;
    #pragma unroll
    for (int s = 32; s > 0; s >>= 1) tot += __shfl_xor(tot, s, 64);
    float target = tot * (1.0f / NE);
    float dev = load - target;
    float sq = dev * dev;
    #pragma unroll
    for (int s = 32; s > 0; s >>= 1) sq += __shfl_xor(sq, s, 64);
    if (e == 0) {
        float lb = sq * (1.0f / NE);
        float z  = ws[NSHADOW * NE] * (1.0f / NTOK);
        out_loss[0] = 0.001f * (lb + z);
    }
}

extern "C" void kernel_launch(void* const* d_in, const int* in_sizes, int n_in,
                              void* d_out, int out_size, void* d_ws, size_t ws_size,
                              hipStream_t stream)
{
    const float* x  = (const float*)d_in[0];
    const float* Wg = (const float*)d_in[1];
    const float* We = (const float*)d_in[2];
    float* out = (float*)d_out;
    float* fw  = out;                                         // [32768, 2]
    float* dm  = out + (size_t)NTOK * 2;                      // [32768, 64]
    float* ls  = out + (size_t)NTOK * 2 + (size_t)NTOK * NE;  // [1]
    float* ws  = (float*)d_ws;

    hipMemsetAsync(ws, 0, (NSHADOW * NE + 1) * sizeof(float), stream);
    router_main<<<NTOK / TPBK, TPB, 0, stream>>>(x, Wg, We, fw, dm, ws);
    router_finalize<<<1, 64, 0, stream>>>(ws, ls);
}